// Round 1
// baseline (454.021 us; speedup 1.0000x reference)
//
#include <hip/hip_runtime.h>

#define D 64  // D_IN == D_HID == 64

// ---------------------------------------------------------------------------
// Kernel 1: zero the aggregation workspace (harness poisons d_ws with 0xAA).
// ---------------------------------------------------------------------------
__global__ void zero_kernel(float4* __restrict__ p, int n4) {
    int i = blockIdx.x * blockDim.x + threadIdx.x;
    if (i < n4) p[i] = make_float4(0.f, 0.f, 0.f, 0.f);
}

// ---------------------------------------------------------------------------
// Kernel 2: edge scatter. 64 lanes per edge; lane d handles feature dim d.
//   agg[dst[e]][d] += w[e] * data[src[e]][d]
// src/dst/w loads are wave-uniform (broadcast); data row load is 256B
// contiguous -> coalesced. atomicAdd is device-scope (cross-XCD safe).
// ---------------------------------------------------------------------------
__global__ void scatter_kernel(const int* __restrict__ src,
                               const int* __restrict__ dst,
                               const float* __restrict__ w,
                               const float* __restrict__ data,
                               float* __restrict__ agg,
                               int E) {
    int tid = blockIdx.x * blockDim.x + threadIdx.x;
    int e = tid >> 6;       // edge index
    int d = tid & 63;       // feature dim
    if (e >= E) return;
    int s = src[e];
    int t = dst[e];
    float val = w[e] * data[s * D + d];
    atomicAdd(&agg[t * D + d], val);
}

// ---------------------------------------------------------------------------
// Kernel 3: out = agg @ theta.  theta (64x64 = 16KB) staged in LDS.
// One wave per output row: lane j computes out[n][j]. agg row loaded
// coalesced (one float per lane), distributed via __shfl across the wave.
// LDS read th[k*64+j]: 64 lanes over 32 banks stride-1 -> 2-way aliasing,
// which is free on gfx950.
// ---------------------------------------------------------------------------
__global__ void gemm_kernel(const float* __restrict__ agg,
                            const float* __restrict__ theta,
                            float* __restrict__ out,
                            int N) {
    __shared__ float th[D * D];
    for (int i = threadIdx.x; i < D * D; i += blockDim.x) th[i] = theta[i];
    __syncthreads();

    int rows_per_block = blockDim.x >> 6;                 // waves per block
    int n = blockIdx.x * rows_per_block + (threadIdx.x >> 6);
    int j = threadIdx.x & 63;
    if (n >= N) return;

    float a = agg[n * D + j];  // coalesced row load, one elem per lane
    float sum = 0.f;
#pragma unroll
    for (int k = 0; k < D; ++k) {
        sum += __shfl(a, k, 64) * th[k * D + j];
    }
    out[n * D + j] = sum;      // coalesced
}

extern "C" void kernel_launch(void* const* d_in, const int* in_sizes, int n_in,
                              void* d_out, int out_size, void* d_ws, size_t ws_size,
                              hipStream_t stream) {
    const int*   src   = (const int*)d_in[0];
    const int*   dst   = (const int*)d_in[1];
    const float* w     = (const float*)d_in[2];
    const float* data  = (const float*)d_in[3];
    const float* theta = (const float*)d_in[4];
    // d_in[5] = num_nodes (device scalar); derive N on host from data size.
    const int E = in_sizes[0];
    const int N = in_sizes[3] / D;

    float* agg = (float*)d_ws;            // N*D floats = 25.6 MB
    float* out = (float*)d_out;

    // 1) zero agg
    {
        int n4 = (N * D) / 4;
        int threads = 256;
        int blocks = (n4 + threads - 1) / threads;
        zero_kernel<<<blocks, threads, 0, stream>>>((float4*)agg, n4);
    }

    // 2) scatter-add weighted source features into agg
    {
        int threads = 256;
        long long total = (long long)E * D;
        int blocks = (int)((total + threads - 1) / threads);
        scatter_kernel<<<blocks, threads, 0, stream>>>(src, dst, w, data, agg, E);
    }

    // 3) dense projection out = agg @ theta
    {
        int threads = 256;                      // 4 rows per block
        int rows_per_block = threads / 64;
        int blocks = (N + rows_per_block - 1) / rows_per_block;
        gemm_kernel<<<blocks, threads, 0, stream>>>(agg, theta, out, N);
    }
}

// Round 2
// 322.609 us; speedup vs baseline: 1.4073x; 1.4073x over previous
//
#include <hip/hip_runtime.h>

#define D 64
#define SCAN_BLOCKS 128
#define SCAN_T 256

// ---------------------------------------------------------------------------
// zero helpers (ws is poisoned 0xAA every launch)
// ---------------------------------------------------------------------------
__global__ void zero_f4_kernel(float4* __restrict__ p, int n4) {
    int i = blockIdx.x * blockDim.x + threadIdx.x;
    if (i < n4) p[i] = make_float4(0.f, 0.f, 0.f, 0.f);
}
__global__ void zero_i_kernel(int* __restrict__ p, int n) {
    int i = blockIdx.x * blockDim.x + threadIdx.x;
    if (i < n) p[i] = 0;
}

// ---------------------------------------------------------------------------
// CSR build: histogram of dst
// ---------------------------------------------------------------------------
__global__ void hist_kernel(const int* __restrict__ dst, int* __restrict__ cnt, int E) {
    int e = blockIdx.x * blockDim.x + threadIdx.x;
    if (e < E) atomicAdd(&cnt[dst[e]], 1);
}

// ---------------------------------------------------------------------------
// scan step 1: per-block chunk sums of cnt -> bsum[SCAN_BLOCKS]
// ---------------------------------------------------------------------------
__global__ void scan_sum_kernel(const int* __restrict__ cnt, int* __restrict__ bsum, int N) {
    __shared__ int sd[SCAN_T];
    int chunk = (N + SCAN_BLOCKS - 1) / SCAN_BLOCKS;
    int lo = blockIdx.x * chunk;
    int hi = min(lo + chunk, N);
    int s = 0;
    for (int i = lo + threadIdx.x; i < hi; i += SCAN_T) s += cnt[i];
    sd[threadIdx.x] = s;
    __syncthreads();
    for (int st = SCAN_T / 2; st > 0; st >>= 1) {
        if ((int)threadIdx.x < st) sd[threadIdx.x] += sd[threadIdx.x + st];
        __syncthreads();
    }
    if (threadIdx.x == 0) bsum[blockIdx.x] = sd[0];
}

// ---------------------------------------------------------------------------
// scan step 2: exclusive scan of bsum -> boff (single block, SCAN_BLOCKS thr)
// also writes rowStart[N] = E
// ---------------------------------------------------------------------------
__global__ void scan_bsum_kernel(const int* __restrict__ bsum, int* __restrict__ boff,
                                 int* __restrict__ rowStartN, int E) {
    __shared__ int sd[SCAN_BLOCKS];
    int t = threadIdx.x;
    sd[t] = bsum[t];
    __syncthreads();
    for (int st = 1; st < SCAN_BLOCKS; st <<= 1) {
        int v = (t >= st) ? sd[t - st] : 0;
        __syncthreads();
        sd[t] += v;
        __syncthreads();
    }
    boff[t] = (t == 0) ? 0 : sd[t - 1];
    if (t == 0) *rowStartN = E;
}

// ---------------------------------------------------------------------------
// scan step 3: per-block exclusive scan of cnt chunk, offset by boff.
// writes rowStart[i] and cursor[i] (cursor is the atomic fill pointer).
// ---------------------------------------------------------------------------
__global__ void scan_final_kernel(const int* __restrict__ cnt, const int* __restrict__ boff,
                                  int* __restrict__ rowStart, int* __restrict__ cursor, int N) {
    __shared__ int sd[SCAN_T];
    int chunk = (N + SCAN_BLOCKS - 1) / SCAN_BLOCKS;
    int lo = blockIdx.x * chunk;
    int hi = min(lo + chunk, N);
    int seg = (chunk + SCAN_T - 1) / SCAN_T;
    int s0 = lo + threadIdx.x * seg;
    int s1 = min(s0 + seg, hi);
    int s = 0;
    for (int i = s0; i < s1; ++i) s += cnt[i];
    sd[threadIdx.x] = s;
    __syncthreads();
    for (int st = 1; st < SCAN_T; st <<= 1) {
        int v = ((int)threadIdx.x >= st) ? sd[threadIdx.x - st] : 0;
        __syncthreads();
        sd[threadIdx.x] += v;
        __syncthreads();
    }
    int run = boff[blockIdx.x] + ((threadIdx.x == 0) ? 0 : sd[threadIdx.x - 1]);
    for (int i = s0; i < s1; ++i) {
        rowStart[i] = run;
        cursor[i] = run;
        run += cnt[i];
    }
}

// ---------------------------------------------------------------------------
// CSR fill: adj[pos] = (src, w) at pos = cursor[dst]++
// ---------------------------------------------------------------------------
__global__ void fill_kernel(const int* __restrict__ src, const int* __restrict__ dst,
                            const float* __restrict__ w, int* __restrict__ cursor,
                            int2* __restrict__ adj, int E) {
    int e = blockIdx.x * blockDim.x + threadIdx.x;
    if (e < E) {
        int t = dst[e];
        int pos = atomicAdd(&cursor[t], 1);
        adj[pos] = make_int2(src[e], __float_as_int(w[e]));
    }
}

// ---------------------------------------------------------------------------
// row GEMM: out[n] = A[n] @ theta  (N x 64 @ 64 x 64)
// theta in LDS; each thread owns one row in 64 VGPRs; theta read via
// broadcast ds_read_b128 (all lanes same address -> conflict-free).
// Fully unrolled so a[] stays in registers (no dynamic indexing).
// ---------------------------------------------------------------------------
__global__ __launch_bounds__(256) void rowgemm_kernel(const float* __restrict__ A,
                                                      const float* __restrict__ theta,
                                                      float* __restrict__ out, int N) {
    __shared__ float th[D * D];
    for (int i = threadIdx.x; i < D * D; i += blockDim.x) th[i] = theta[i];
    __syncthreads();

    int n = blockIdx.x * blockDim.x + threadIdx.x;
    if (n >= N) return;

    float a[D];
    const float4* ar = (const float4*)(A + (size_t)n * D);
#pragma unroll
    for (int i = 0; i < D / 4; ++i) {
        float4 v = ar[i];
        a[4 * i] = v.x; a[4 * i + 1] = v.y; a[4 * i + 2] = v.z; a[4 * i + 3] = v.w;
    }

    float4* orow = (float4*)(out + (size_t)n * D);
#pragma unroll
    for (int jc = 0; jc < 4; ++jc) {
        float4 acc[4];
#pragma unroll
        for (int q = 0; q < 4; ++q) acc[q] = make_float4(0.f, 0.f, 0.f, 0.f);
#pragma unroll
        for (int k = 0; k < D; ++k) {
            float av = a[k];
#pragma unroll
            for (int q = 0; q < 4; ++q) {
                float4 b = *(const float4*)&th[k * D + jc * 16 + 4 * q];
                acc[q].x += av * b.x;
                acc[q].y += av * b.y;
                acc[q].z += av * b.z;
                acc[q].w += av * b.w;
            }
        }
#pragma unroll
        for (int q = 0; q < 4; ++q) orow[jc * 4 + q] = acc[q];
    }
}

// ---------------------------------------------------------------------------
// gather: one wave per node; lane d: out[n][d] = sum_e w_e * proj[src_e][d]
// adj entry load is wave-uniform broadcast; proj row load is 256B coalesced.
// ---------------------------------------------------------------------------
__global__ void gather_kernel(const int* __restrict__ rowStart, const int2* __restrict__ adj,
                              const float* __restrict__ proj, float* __restrict__ out, int N) {
    int wid = (blockIdx.x * blockDim.x + threadIdx.x) >> 6;
    int lane = threadIdx.x & 63;
    if (wid >= N) return;
    int beg = rowStart[wid];
    int end = rowStart[wid + 1];
    float acc0 = 0.f, acc1 = 0.f;
    int e = beg;
    for (; e + 1 < end; e += 2) {
        int2 e0 = adj[e];
        int2 e1 = adj[e + 1];
        acc0 += __int_as_float(e0.y) * proj[(size_t)e0.x * D + lane];
        acc1 += __int_as_float(e1.y) * proj[(size_t)e1.x * D + lane];
    }
    if (e < end) {
        int2 e0 = adj[e];
        acc0 += __int_as_float(e0.y) * proj[(size_t)e0.x * D + lane];
    }
    out[(size_t)wid * D + lane] = acc0 + acc1;
}

// ---------------------------------------------------------------------------
// fallback scatter (round-1) if ws is too small for the CSR path
// ---------------------------------------------------------------------------
__global__ void scatter_kernel(const int* __restrict__ src, const int* __restrict__ dst,
                               const float* __restrict__ w, const float* __restrict__ data,
                               float* __restrict__ agg, int E) {
    int tid = blockIdx.x * blockDim.x + threadIdx.x;
    int e = tid >> 6;
    int d = tid & 63;
    if (e >= E) return;
    float val = w[e] * data[(size_t)src[e] * D + d];
    atomicAdd(&agg[(size_t)dst[e] * D + d], val);
}

extern "C" void kernel_launch(void* const* d_in, const int* in_sizes, int n_in,
                              void* d_out, int out_size, void* d_ws, size_t ws_size,
                              hipStream_t stream) {
    const int*   src   = (const int*)d_in[0];
    const int*   dst   = (const int*)d_in[1];
    const float* w     = (const float*)d_in[2];
    const float* data  = (const float*)d_in[3];
    const float* theta = (const float*)d_in[4];
    const int E = in_sizes[0];
    const int N = in_sizes[3] / D;
    float* out = (float*)d_out;

    // ws layout (CSR path): proj | adj | cnt | rowStart | cursor | bsum | boff
    size_t need = (size_t)N * D * 4 + (size_t)E * 8 + ((size_t)N + 1) * 4 * 2
                + (size_t)N * 4 + SCAN_BLOCKS * 4 * 2 + 256;

    if (ws_size >= need) {
        float* proj     = (float*)d_ws;
        int2*  adj      = (int2*)(proj + (size_t)N * D);
        int*   cnt      = (int*)(adj + E);
        int*   rowStart = cnt + (N + 1);
        int*   cursor   = rowStart + (N + 1);
        int*   bsum     = cursor + N;
        int*   boff     = bsum + SCAN_BLOCKS;

        // zero cnt
        zero_i_kernel<<<(N + 1 + 255) / 256, 256, 0, stream>>>(cnt, N + 1);
        // histogram of dst
        hist_kernel<<<(E + 255) / 256, 256, 0, stream>>>(dst, cnt, E);
        // scan: block sums -> exclusive block offsets -> final prefix
        scan_sum_kernel<<<SCAN_BLOCKS, SCAN_T, 0, stream>>>(cnt, bsum, N);
        scan_bsum_kernel<<<1, SCAN_BLOCKS, 0, stream>>>(bsum, boff, rowStart + N, E);
        scan_final_kernel<<<SCAN_BLOCKS, SCAN_T, 0, stream>>>(cnt, boff, rowStart, cursor, N);
        // fill adjacency
        fill_kernel<<<(E + 255) / 256, 256, 0, stream>>>(src, dst, w, cursor, adj, E);
        // proj = data @ theta
        rowgemm_kernel<<<(N + 255) / 256, 256, 0, stream>>>(data, theta, proj, N);
        // out[n] = sum_e w_e * proj[src_e]
        gather_kernel<<<(N + 3) / 4, 256, 0, stream>>>(rowStart, adj, proj, out, N);
    } else {
        // fallback: zero agg + atomic scatter + row GEMM
        float* agg = (float*)d_ws;
        int n4 = (N * D) / 4;
        zero_f4_kernel<<<(n4 + 255) / 256, 256, 0, stream>>>((float4*)agg, n4);
        long long total = (long long)E * D;
        scatter_kernel<<<(int)((total + 255) / 256), 256, 0, stream>>>(src, dst, w, data, agg, E);
        rowgemm_kernel<<<(N + 255) / 256, 256, 0, stream>>>(agg, theta, out, N);
    }
}

// Round 3
// 320.546 us; speedup vs baseline: 1.4164x; 1.0064x over previous
//
#include <hip/hip_runtime.h>

#define D 64
#define SCAN_BLOCKS 128
#define SCAN_T 256

// ---------------------------------------------------------------------------
// zero helper (ws is poisoned 0xAA every launch)
// ---------------------------------------------------------------------------
__global__ void zero_i_kernel(int* __restrict__ p, int n) {
    int i = blockIdx.x * blockDim.x + threadIdx.x;
    if (i < n) p[i] = 0;
}
__global__ void zero_f4_kernel(float4* __restrict__ p, int n4) {
    int i = blockIdx.x * blockDim.x + threadIdx.x;
    if (i < n4) p[i] = make_float4(0.f, 0.f, 0.f, 0.f);
}

// ---------------------------------------------------------------------------
// CSR build: histogram of dst
// ---------------------------------------------------------------------------
__global__ void hist_kernel(const int* __restrict__ dst, int* __restrict__ cnt, int E) {
    int e = blockIdx.x * blockDim.x + threadIdx.x;
    if (e < E) atomicAdd(&cnt[dst[e]], 1);
}

// ---------------------------------------------------------------------------
// scan step 1: per-block chunk sums of cnt -> bsum[SCAN_BLOCKS]
// ---------------------------------------------------------------------------
__global__ void scan_sum_kernel(const int* __restrict__ cnt, int* __restrict__ bsum, int N) {
    __shared__ int sd[SCAN_T];
    int chunk = (N + SCAN_BLOCKS - 1) / SCAN_BLOCKS;
    int lo = blockIdx.x * chunk;
    int hi = min(lo + chunk, N);
    int s = 0;
    for (int i = lo + threadIdx.x; i < hi; i += SCAN_T) s += cnt[i];
    sd[threadIdx.x] = s;
    __syncthreads();
    for (int st = SCAN_T / 2; st > 0; st >>= 1) {
        if ((int)threadIdx.x < st) sd[threadIdx.x] += sd[threadIdx.x + st];
        __syncthreads();
    }
    if (threadIdx.x == 0) bsum[blockIdx.x] = sd[0];
}

// ---------------------------------------------------------------------------
// scan step 2: exclusive scan of bsum -> boff; also rowStart[N] = E
// ---------------------------------------------------------------------------
__global__ void scan_bsum_kernel(const int* __restrict__ bsum, int* __restrict__ boff,
                                 int* __restrict__ rowStartN, int E) {
    __shared__ int sd[SCAN_BLOCKS];
    int t = threadIdx.x;
    sd[t] = bsum[t];
    __syncthreads();
    for (int st = 1; st < SCAN_BLOCKS; st <<= 1) {
        int v = (t >= st) ? sd[t - st] : 0;
        __syncthreads();
        sd[t] += v;
        __syncthreads();
    }
    boff[t] = (t == 0) ? 0 : sd[t - 1];
    if (t == 0) *rowStartN = E;
}

// ---------------------------------------------------------------------------
// scan step 3: per-block exclusive scan of cnt chunk, offset by boff.
// ---------------------------------------------------------------------------
__global__ void scan_final_kernel(const int* __restrict__ cnt, const int* __restrict__ boff,
                                  int* __restrict__ rowStart, int* __restrict__ cursor, int N) {
    __shared__ int sd[SCAN_T];
    int chunk = (N + SCAN_BLOCKS - 1) / SCAN_BLOCKS;
    int lo = blockIdx.x * chunk;
    int hi = min(lo + chunk, N);
    int seg = (chunk + SCAN_T - 1) / SCAN_T;
    int s0 = lo + threadIdx.x * seg;
    int s1 = min(s0 + seg, hi);
    int s = 0;
    for (int i = s0; i < s1; ++i) s += cnt[i];
    sd[threadIdx.x] = s;
    __syncthreads();
    for (int st = 1; st < SCAN_T; st <<= 1) {
        int v = ((int)threadIdx.x >= st) ? sd[threadIdx.x - st] : 0;
        __syncthreads();
        sd[threadIdx.x] += v;
        __syncthreads();
    }
    int run = boff[blockIdx.x] + ((threadIdx.x == 0) ? 0 : sd[threadIdx.x - 1]);
    for (int i = s0; i < s1; ++i) {
        rowStart[i] = run;
        cursor[i] = run;
        run += cnt[i];
    }
}

// ---------------------------------------------------------------------------
// CSR fill: adj[pos] = (src, w) at pos = cursor[dst]++
// ---------------------------------------------------------------------------
__global__ void fill_kernel(const int* __restrict__ src, const int* __restrict__ dst,
                            const float* __restrict__ w, int* __restrict__ cursor,
                            int2* __restrict__ adj, int E) {
    int e = blockIdx.x * blockDim.x + threadIdx.x;
    if (e < E) {
        int t = dst[e];
        int pos = atomicAdd(&cursor[t], 1);
        adj[pos] = make_int2(src[e], __float_as_int(w[e]));
    }
}

// ---------------------------------------------------------------------------
// Tiled row GEMM: out = A @ theta (N x 64 @ 64 x 64).
// Block handles 64 rows. A tile staged TRANSPOSED in LDS (at[k][row], pad 68
// keeps b128 16B-aligned); theta in LDS. Thread t computes rows r0..r0+3 x
// cols c0..c0+3: per k one broadcast b128 (at) + one 2-way-aliased b128 (th),
// 16 FMA -> 128 ds_read_b128 : 1024 v_fma per wave. Coalesced global I/O.
// ---------------------------------------------------------------------------
__global__ __launch_bounds__(256) void rowgemm_kernel(const float* __restrict__ A,
                                                      const float* __restrict__ theta,
                                                      float* __restrict__ out, int N) {
    __shared__ float th[D * D];
    __shared__ float at[D][68];
    int t = threadIdx.x;
    int rowBase = blockIdx.x * 64;

#pragma unroll
    for (int i = 0; i < 4; ++i) {
        int f = t + i * 256;                 // 0..1023 float4 index
        ((float4*)th)[f] = ((const float4*)theta)[f];
    }
#pragma unroll
    for (int i = 0; i < 4; ++i) {
        int f = t + i * 256;                 // 0..1023
        int row = f >> 4;                    // 0..63
        int kv = f & 15;                     // float4 group in k
        float4 v = make_float4(0.f, 0.f, 0.f, 0.f);
        if (rowBase + row < N) v = *(const float4*)&A[(size_t)(rowBase + row) * D + kv * 4];
        at[kv * 4 + 0][row] = v.x;
        at[kv * 4 + 1][row] = v.y;
        at[kv * 4 + 2][row] = v.z;
        at[kv * 4 + 3][row] = v.w;
    }
    __syncthreads();

    int c0 = (t & 15) * 4;
    int r0 = (t >> 4) * 4;
    float4 acc0 = make_float4(0.f, 0.f, 0.f, 0.f);
    float4 acc1 = acc0, acc2 = acc0, acc3 = acc0;

#pragma unroll
    for (int k = 0; k < D; ++k) {
        float4 bv = *(const float4*)&th[k * D + c0];
        float4 av = *(const float4*)&at[k][r0];
        acc0.x += av.x * bv.x; acc0.y += av.x * bv.y; acc0.z += av.x * bv.z; acc0.w += av.x * bv.w;
        acc1.x += av.y * bv.x; acc1.y += av.y * bv.y; acc1.z += av.y * bv.z; acc1.w += av.y * bv.w;
        acc2.x += av.z * bv.x; acc2.y += av.z * bv.y; acc2.z += av.z * bv.z; acc2.w += av.z * bv.w;
        acc3.x += av.w * bv.x; acc3.y += av.w * bv.y; acc3.z += av.w * bv.z; acc3.w += av.w * bv.w;
    }

    float4 accs[4] = {acc0, acc1, acc2, acc3};
#pragma unroll
    for (int i = 0; i < 4; ++i) {
        int r = rowBase + r0 + i;
        if (r < N) *(float4*)&out[(size_t)r * D + c0] = accs[i];
    }
}

// ---------------------------------------------------------------------------
// gather: one wave per node. Lanes cooperatively load up to 64 adj entries
// in ONE coalesced 8B/lane load, then broadcast each entry via __shfl.
// proj row loads are 256B coalesced; dual accumulators break the FMA chain.
// ---------------------------------------------------------------------------
__global__ void gather_kernel(const int* __restrict__ rowStart, const int2* __restrict__ adj,
                              const float* __restrict__ proj, float* __restrict__ out, int N) {
    int wid = (blockIdx.x * blockDim.x + threadIdx.x) >> 6;
    int lane = threadIdx.x & 63;
    if (wid >= N) return;
    int beg = rowStart[wid];
    int end = rowStart[wid + 1];
    float acc0 = 0.f, acc1 = 0.f;
    for (int base = beg; base < end; base += 64) {
        int cnt = min(64, end - base);
        int sx = 0; float wv = 0.f;
        if (lane < cnt) {
            int2 a = adj[base + lane];
            sx = a.x;
            wv = __int_as_float(a.y);
        }
        int j = 0;
        for (; j + 1 < cnt; j += 2) {
            int   s0 = __shfl(sx, j, 64);
            float w0 = __shfl(wv, j, 64);
            int   s1 = __shfl(sx, j + 1, 64);
            float w1 = __shfl(wv, j + 1, 64);
            acc0 += w0 * proj[(size_t)s0 * D + lane];
            acc1 += w1 * proj[(size_t)s1 * D + lane];
        }
        if (j < cnt) {
            int   s0 = __shfl(sx, j, 64);
            float w0 = __shfl(wv, j, 64);
            acc0 += w0 * proj[(size_t)s0 * D + lane];
        }
    }
    out[(size_t)wid * D + lane] = acc0 + acc1;
}

// ---------------------------------------------------------------------------
// fallback scatter if ws too small for CSR path
// ---------------------------------------------------------------------------
__global__ void scatter_kernel(const int* __restrict__ src, const int* __restrict__ dst,
                               const float* __restrict__ w, const float* __restrict__ data,
                               float* __restrict__ agg, int E) {
    int tid = blockIdx.x * blockDim.x + threadIdx.x;
    int e = tid >> 6;
    int d = tid & 63;
    if (e >= E) return;
    float val = w[e] * data[(size_t)src[e] * D + d];
    atomicAdd(&agg[(size_t)dst[e] * D + d], val);
}

extern "C" void kernel_launch(void* const* d_in, const int* in_sizes, int n_in,
                              void* d_out, int out_size, void* d_ws, size_t ws_size,
                              hipStream_t stream) {
    const int*   src   = (const int*)d_in[0];
    const int*   dst   = (const int*)d_in[1];
    const float* w     = (const float*)d_in[2];
    const float* data  = (const float*)d_in[3];
    const float* theta = (const float*)d_in[4];
    const int E = in_sizes[0];
    const int N = in_sizes[3] / D;
    float* out = (float*)d_out;

    // ws layout (CSR path): proj | adj | cnt | rowStart | cursor | bsum | boff
    size_t need = (size_t)N * D * 4 + (size_t)E * 8 + ((size_t)N + 1) * 4 * 2
                + (size_t)N * 4 + SCAN_BLOCKS * 4 * 2 + 256;

    if (ws_size >= need) {
        float* proj     = (float*)d_ws;
        int2*  adj      = (int2*)(proj + (size_t)N * D);
        int*   cnt      = (int*)(adj + E);
        int*   rowStart = cnt + (N + 1);
        int*   cursor   = rowStart + (N + 1);
        int*   bsum     = cursor + N;
        int*   boff     = bsum + SCAN_BLOCKS;

        zero_i_kernel<<<(N + 1 + 255) / 256, 256, 0, stream>>>(cnt, N + 1);
        hist_kernel<<<(E + 255) / 256, 256, 0, stream>>>(dst, cnt, E);
        scan_sum_kernel<<<SCAN_BLOCKS, SCAN_T, 0, stream>>>(cnt, bsum, N);
        scan_bsum_kernel<<<1, SCAN_BLOCKS, 0, stream>>>(bsum, boff, rowStart + N, E);
        scan_final_kernel<<<SCAN_BLOCKS, SCAN_T, 0, stream>>>(cnt, boff, rowStart, cursor, N);
        fill_kernel<<<(E + 255) / 256, 256, 0, stream>>>(src, dst, w, cursor, adj, E);
        rowgemm_kernel<<<(N + 63) / 64, 256, 0, stream>>>(data, theta, proj, N);
        gather_kernel<<<(N + 3) / 4, 256, 0, stream>>>(rowStart, adj, proj, out, N);
    } else {
        float* agg = (float*)d_ws;
        int n4 = (N * D) / 4;
        zero_f4_kernel<<<(n4 + 255) / 256, 256, 0, stream>>>((float4*)agg, n4);
        long long total = (long long)E * D;
        scatter_kernel<<<(int)((total + 255) / 256), 256, 0, stream>>>(src, dst, w, data, agg, E);
        rowgemm_kernel<<<(N + 63) / 64, 256, 0, stream>>>(agg, theta, out, N);
    }
}